// Round 6
// baseline (128.821 us; speedup 1.0000x reference)
//
#include <hip/hip_runtime.h>

// ---------------------------------------------------------------------------
// SelfAttention (1x1x1 conv QKV + softmax attention), B=2, C=128, N=4096
// I/O: fp32. Internal: bf16 MFMA + fp32 accum. No max-shift softmax.
// Round-15 = round-14 (verified, 112.4us) + V-DIRECT: V is no longer staged
// in LDS. PV B-fragments load straight from global Vo (L2/L1-resident,
// 16KB tile re-read by 4 waves -> L1 hits). This halves K2's LDS-pipe
// volume (160->80 KB/block-iter) and moves V onto the concurrent
// vector-memory path. Fragment address = the verified staging formula.
//  - K: LDS double-buffered, XOR-swizzled, reg-staged, 1 barrier/k-tile.
//  - P: never touches LDS (exp2 -> cvt_pk -> permlane32/16 swaps).
//  - V: direct global loads, ks=0 issued before QK (latency under MFMA).
// LDS: 2 x 16384 (K only) = 32768 B.
// K1 qkv_proj : grid (64,2,3)  -> Qt[b][n][c] (x log2e), Kt, Vo bf16
// K2 attn_part: grid (32,2,8)  -> split-K partials (bf16) + l (fp32)
// K3 combine  : grid (64,2,4)  -> sum partials, /l, out[b][c][n] fp32
// ---------------------------------------------------------------------------

typedef __bf16 bf16x8 __attribute__((ext_vector_type(8)));
typedef __bf16 bf16x4v __attribute__((ext_vector_type(4)));
typedef float  f32x4  __attribute__((ext_vector_type(4)));

#define LDP 136   // row stride (bf16) for K1's 128-wide rows; 272B
#define LDO 33    // row stride (f32) for combine transpose (32-wide rows)

constexpr int CB = 128;
constexpr int NB = 4096;
constexpr int BB = 2;

__device__ __forceinline__ bf16x8 ldfrag(const __bf16* lds, int row, int koff, int ld) {
  return *(const bf16x8*)(lds + row * ld + koff);
}

__device__ __forceinline__ unsigned cvt_pk_bf16(float lo, float hi) {
  unsigned w;
  asm("v_cvt_pk_bf16_f32 %0, %1, %2" : "=v"(w) : "v"(lo), "v"(hi));
  return w;
}

// ---------------------------------------------------------------------------
// K1: QKV projection. blockIdx.z picks which of {Q,K,V}. One barrier total.
// LDS: xT[64][LDP] + Wl[128][LDP] = 52224 B.
// Q output is pre-scaled by log2(e) so K2 can use exp2 directly.
// ---------------------------------------------------------------------------
__global__ __launch_bounds__(256) void qkv_proj_kernel(
    const float* __restrict__ x,
    const float* __restrict__ Wq, const float* __restrict__ bq,
    const float* __restrict__ Wk, const float* __restrict__ bk,
    const float* __restrict__ Wv, const float* __restrict__ bv,
    __bf16* __restrict__ Qt, __bf16* __restrict__ Kt, __bf16* __restrict__ Vo)
{
  extern __shared__ __align__(16) char smem_raw[];
  __bf16* xT = (__bf16*)smem_raw;   // xT[i][c]
  __bf16* Wl = xT + 64 * LDP;       // Wl[o][c]

  const int b  = blockIdx.y;
  const int n0 = blockIdx.x * 64;
  const int m  = blockIdx.z;        // 0=Q, 1=K, 2=V
  const int t  = threadIdx.x;
  const int lane = t & 63, w = t >> 6;
  const int l15 = lane & 15, quad = lane >> 4;

  const float* W = (m == 0) ? Wq : (m == 1) ? Wk : Wv;
  const float* bias_p = (m == 0) ? bq : (m == 1) ? bk : bv;
  const float qscale = (m == 0) ? 1.4426950408889634f : 1.0f;

  for (int v = t; v < 2048; v += 256) {
    int c = v >> 4, i4 = v & 15;
    float4 d = *(const float4*)(x + (b * CB + c) * NB + n0 + i4 * 4);
    xT[(i4 * 4 + 0) * LDP + c] = (__bf16)d.x;
    xT[(i4 * 4 + 1) * LDP + c] = (__bf16)d.y;
    xT[(i4 * 4 + 2) * LDP + c] = (__bf16)d.z;
    xT[(i4 * 4 + 3) * LDP + c] = (__bf16)d.w;
  }
  for (int v = t; v < 4096; v += 256) {
    int o = v >> 5, c4 = v & 31;
    float4 d = *(const float4*)(W + o * 128 + c4 * 4);
    bf16x4v u = {(__bf16)d.x, (__bf16)d.y, (__bf16)d.z, (__bf16)d.w};
    *(bf16x4v*)(Wl + o * LDP + c4 * 4) = u;
  }
  __syncthreads();

  if (m < 2) {
    f32x4 acc[8];
#pragma unroll
    for (int ct = 0; ct < 8; ct++) acc[ct] = (f32x4)0.0f;
#pragma unroll
    for (int ks = 0; ks < 4; ks++) {
      int koff = ks * 32 + quad * 8;
      bf16x8 a = ldfrag(xT, w * 16 + l15, koff, LDP);
#pragma unroll
      for (int ct = 0; ct < 8; ct++) {
        bf16x8 bb = ldfrag(Wl, ct * 16 + l15, koff, LDP);
        acc[ct] = __builtin_amdgcn_mfma_f32_16x16x32_bf16(a, bb, acc[ct], 0, 0, 0);
      }
    }
    __bf16* O = (m == 0) ? Qt : Kt;
#pragma unroll
    for (int ct = 0; ct < 8; ct++) {
      int o = ct * 16 + l15;
      float bias = bias_p[o];
#pragma unroll
      for (int r = 0; r < 4; r++) {
        int i = w * 16 + quad * 4 + r;
        O[(b * NB + n0 + i) * CB + o] = (__bf16)((acc[ct][r] + bias) * qscale);
      }
    }
  } else {
    f32x4 acc[2][4];
#pragma unroll
    for (int rr = 0; rr < 2; rr++)
#pragma unroll
      for (int ct = 0; ct < 4; ct++) acc[rr][ct] = (f32x4)0.0f;
#pragma unroll
    for (int ks = 0; ks < 4; ks++) {
      int koff = ks * 32 + quad * 8;
      bf16x8 a0 = ldfrag(Wl, (w * 2 + 0) * 16 + l15, koff, LDP);
      bf16x8 a1 = ldfrag(Wl, (w * 2 + 1) * 16 + l15, koff, LDP);
#pragma unroll
      for (int ct = 0; ct < 4; ct++) {
        bf16x8 bb = ldfrag(xT, ct * 16 + l15, koff, LDP);
        acc[0][ct] = __builtin_amdgcn_mfma_f32_16x16x32_bf16(a0, bb, acc[0][ct], 0, 0, 0);
        acc[1][ct] = __builtin_amdgcn_mfma_f32_16x16x32_bf16(a1, bb, acc[1][ct], 0, 0, 0);
      }
    }
#pragma unroll
    for (int rr = 0; rr < 2; rr++)
#pragma unroll
      for (int ct = 0; ct < 4; ct++)
#pragma unroll
        for (int r = 0; r < 4; r++) {
          int o = (w * 2 + rr) * 16 + quad * 4 + r;
          int i = ct * 16 + l15;
          Vo[(b * CB + o) * NB + n0 + i] = (__bf16)(acc[rr][ct][r] + bias_p[o]);
        }
  }
}

// ---------------------------------------------------------------------------
// K2: split-K attention partials, no max-shift. grid (32, 2, nsplit), 256 thr
// (4 waves x 32 q-rows = 128 q-rows/block, each wave: two 16-row q-tiles).
// Swapped QK^T (S^T = mfma(K,Q)) -> lane (quad,l15) holds P[16kt+4*quad+r][l15].
// P -> PV A-fragment in registers via v_permlane{32,16}_swap (verified r14).
// K: LDS double-buffered, XOR-swizzled (16B units, ^(row&7)<<4), reg-staged,
//    loads at top of iter, write-to-idle-buffer after compute, 1 barrier/iter.
// V: DIRECT global loads as PV B-frags (L2/L1-resident; same address formula
//    as the old staging load): V[c=tt*16+l15][k=m0+ks*32+quad*8+j].
//    ks=0 frags issued before QK so L2 latency hides under MFMA.
// LDS: 2 x 16384 (K only) = 32768 B.
// ---------------------------------------------------------------------------
__global__ __launch_bounds__(256, 2) void attn_part_kernel(
    const __bf16* __restrict__ Qt,
    const __bf16* __restrict__ Kt,
    const __bf16* __restrict__ Vo,
    __bf16* __restrict__ Opart, float* __restrict__ Ll, int ksz)
{
  extern __shared__ __align__(16) char smem_raw[];
  // buffer bf: K at bf*16384

  const int b  = blockIdx.y;
  const int q0 = blockIdx.x * 128;
  const int s  = blockIdx.z;
  const int k_base = s * ksz;
  const int nit = ksz >> 6;
  const int t  = threadIdx.x;
  const int lane = t & 63, w = t >> 6;             // w = 0..3
  const int l15 = lane & 15, quad = lane >> 4;
  const int row0 = w * 32;                         // wave's first local q-row
  const int xsw = (l15 & 7) << 4;                  // read-side swizzle term

  // Q fragments: two 16-row q-tiles per wave (MFMA B-operand layout).
  bf16x8 qf[2][4];
#pragma unroll
  for (int qt = 0; qt < 2; qt++)
#pragma unroll
    for (int cb = 0; cb < 4; cb++)
      qf[qt][cb] = *(const bf16x8*)(Qt +
          (size_t)(b * NB + q0 + row0 + qt * 16 + l15) * CB + cb * 32 + quad * 8);

  // Per-wave V fragment base: row c = tt*16 + l15, k-offset quad*8.
  const __bf16* Vbase = Vo + (size_t)(b * CB + l15) * NB + quad * 8;

  bf16x8 kr[4];
  // Global loads of one 64-row K tile into regs (4 bf16x8 per thread).
  auto load_ktile = [&](int m0) {
#pragma unroll
    for (int u = 0; u < 4; u++) {
      int v = t + u * 256;
      int j = v >> 4, c8 = v & 15;
      kr[u] = *(const bf16x8*)(Kt + (size_t)(b * NB + m0 + j) * CB + c8 * 8);
    }
  };
  // Swizzled LDS write of the staged K regs into buffer bf.
  auto write_ktile = [&](int bf) {
    char* Kn = smem_raw + bf * 16384;
#pragma unroll
    for (int u = 0; u < 4; u++) {
      int v = t + u * 256;
      int j = v >> 4, c8 = v & 15;
      *(bf16x8*)(Kn + j * 256 + ((c8 * 16) ^ ((j & 7) << 4))) = kr[u];
    }
  };

  float lsum[2] = {0.0f, 0.0f};
  f32x4 o_acc[2][8];
#pragma unroll
  for (int qt = 0; qt < 2; qt++)
#pragma unroll
    for (int tt = 0; tt < 8; tt++) o_acc[qt][tt] = (f32x4)0.0f;

  // Stage tile 0 into buffer 0.
  load_ktile(k_base);
  write_ktile(0);
  __syncthreads();

  int cur = 0;
  for (int it = 0; it < nit; it++) {
    const int m0 = k_base + it * 64;

    // Issue next K tile's global loads now; LDS write happens after compute.
    if (it + 1 < nit) load_ktile(m0 + 64);

    // Issue V ks=0 fragments for THIS iter; QK phase covers the latency.
    bf16x8 vb0[8];
#pragma unroll
    for (int tt = 0; tt < 8; tt++)
      vb0[tt] = *(const bf16x8*)(Vbase + (size_t)(tt * 16) * NB + m0);

    const char* Kc = smem_raw + cur * 16384;

    // S^T[64k x 32q] per wave: A = K-frag (row = k), B = Q-frag (col = q).
    f32x4 sacc[2][4];               // [qt][kt]
#pragma unroll
    for (int qt = 0; qt < 2; qt++)
#pragma unroll
      for (int kt = 0; kt < 4; kt++) sacc[qt][kt] = (f32x4)0.0f;
#pragma unroll
    for (int cb = 0; cb < 4; cb++) {
      const int xo = (cb * 64 + quad * 16) ^ xsw;
#pragma unroll
      for (int kt = 0; kt < 4; kt++) {
        bf16x8 af = *(const bf16x8*)(Kc + (kt * 16 + l15) * 256 + xo);
        sacc[0][kt] = __builtin_amdgcn_mfma_f32_16x16x32_bf16(af, qf[0][cb], sacc[0][kt], 0, 0, 0);
        sacc[1][kt] = __builtin_amdgcn_mfma_f32_16x16x32_bf16(af, qf[1][cb], sacc[1][kt], 0, 0, 0);
      }
    }

    // P = exp2(S^T) (Q carried log2e); build PV A-frags in-register.
    bf16x8 pa[2][2];                // [qt][ks]
#pragma unroll
    for (int qt = 0; qt < 2; qt++) {
      unsigned d[4][2];
#pragma unroll
      for (int kt = 0; kt < 4; kt++) {
        float p0 = exp2f(sacc[qt][kt][0]);
        float p1 = exp2f(sacc[qt][kt][1]);
        float p2 = exp2f(sacc[qt][kt][2]);
        float p3 = exp2f(sacc[qt][kt][3]);
        lsum[qt] += (p0 + p1) + (p2 + p3);
        d[kt][0] = cvt_pk_bf16(p0, p1);
        d[kt][1] = cvt_pk_bf16(p2, p3);
      }
#pragma unroll
      for (int ks = 0; ks < 2; ks++) {
        unsigned a0 = d[2 * ks][0], a1 = d[2 * ks][1];
        unsigned b0 = d[2 * ks + 1][0], b1 = d[2 * ks + 1][1];
        // vdst = a (d[2ks]), vsrc = b (d[2ks+1]):
        //   swap32: a=(a.q0,a.q1,b.q0,b.q1), b=(a.q2,a.q3,b.q2,b.q3)
        //   swap16: a=(a.q0,a.q2,b.q0,b.q2), b=(a.q1,a.q3,b.q1,b.q3)
        asm("v_permlane32_swap_b32 %0, %1" : "+v"(a0), "+v"(b0));
        asm("v_permlane16_swap_b32 %0, %1" : "+v"(a0), "+v"(b0));
        asm("v_permlane32_swap_b32 %0, %1" : "+v"(a1), "+v"(b1));
        asm("v_permlane16_swap_b32 %0, %1" : "+v"(a1), "+v"(b1));
        union { unsigned u[4]; bf16x8 v; } pk;
        pk.u[0] = a0; pk.u[1] = a1; pk.u[2] = b0; pk.u[3] = b1;
        pa[qt][ks] = pk.v;
      }
    }

    // Issue V ks=1 fragments, then PV ks=0 MFMAs cover their latency.
    bf16x8 vb1[8];
#pragma unroll
    for (int tt = 0; tt < 8; tt++)
      vb1[tt] = *(const bf16x8*)(Vbase + (size_t)(tt * 16) * NB + m0 + 32);

    // O += P * V (V fragments straight from L1/L2).
#pragma unroll
    for (int tt = 0; tt < 8; tt++) {
      o_acc[0][tt] = __builtin_amdgcn_mfma_f32_16x16x32_bf16(pa[0][0], vb0[tt], o_acc[0][tt], 0, 0, 0);
      o_acc[1][tt] = __builtin_amdgcn_mfma_f32_16x16x32_bf16(pa[1][0], vb0[tt], o_acc[1][tt], 0, 0, 0);
    }
#pragma unroll
    for (int tt = 0; tt < 8; tt++) {
      o_acc[0][tt] = __builtin_amdgcn_mfma_f32_16x16x32_bf16(pa[0][1], vb1[tt], o_acc[0][tt], 0, 0, 0);
      o_acc[1][tt] = __builtin_amdgcn_mfma_f32_16x16x32_bf16(pa[1][1], vb1[tt], o_acc[1][tt], 0, 0, 0);
    }

    // Write next K tile into the IDLE buffer; one barrier hands it over.
    if (it + 1 < nit) {
      write_ktile(cur ^ 1);
      __syncthreads();
      cur ^= 1;
    }
  }

  // l-sum: lane holds the partial over its 16 k-slots; reduce across quads.
#pragma unroll
  for (int qt = 0; qt < 2; qt++) {
    lsum[qt] += __shfl_xor(lsum[qt], 16);
    lsum[qt] += __shfl_xor(lsum[qt], 32);
  }

  // Write unnormalized partial O (bf16, C/D layout direct) and l (fp32).
  const size_t obase = ((size_t)(s * BB + b) * NB + q0) * CB;
#pragma unroll
  for (int qt = 0; qt < 2; qt++)
#pragma unroll
    for (int tt = 0; tt < 8; tt++)
#pragma unroll
      for (int r = 0; r < 4; r++)
        Opart[obase + (size_t)(row0 + qt * 16 + quad * 4 + r) * CB + tt * 16 + l15] =
            (__bf16)o_acc[qt][tt][r];
  if (quad == 0) {
    const size_t lbase = (size_t)(s * BB + b) * NB + q0 + row0;
#pragma unroll
    for (int qt = 0; qt < 2; qt++)
      Ll[lbase + qt * 16 + l15] = lsum[qt];
  }
}

// ---------------------------------------------------------------------------
// K3: combine bf16 partials + normalize + transpose -> out[b][c][n] fp32.
// grid (64, 2, 4): 64 n-rows x 32 channels per block, 256 thr.
// LDS: Olf[64][LDO] f32 = 8448 B.
// ---------------------------------------------------------------------------
__global__ __launch_bounds__(256) void combine_kernel(
    const __bf16* __restrict__ Opart, const float* __restrict__ Ll,
    float* __restrict__ out, int nsplit)
{
  extern __shared__ __align__(16) char smem_raw[];
  float* Olf = (float*)smem_raw;  // Olf[i][c'], c' in [0,32)

  const int b  = blockIdx.y;
  const int n0 = blockIdx.x * 64;
  const int c0 = blockIdx.z * 32;
  const int t  = threadIdx.x;
  const int i  = t >> 2;          // row 0..63
  const int cc = (t & 3) * 8;     // 8 channels per thread

  float L = 0.0f;
  for (int s = 0; s < nsplit; s++)
    L += Ll[(size_t)(s * BB + b) * NB + n0 + i];

  float acc[8];
#pragma unroll
  for (int u = 0; u < 8; u++) acc[u] = 0.0f;
  for (int s = 0; s < nsplit; s++) {
    bf16x8 d = *(const bf16x8*)(Opart +
        ((size_t)(s * BB + b) * NB + n0 + i) * CB + c0 + cc);
#pragma unroll
    for (int u = 0; u < 8; u++) acc[u] += (float)d[u];
  }
  float invL = 1.0f / L;
#pragma unroll
  for (int u = 0; u < 8; u++) Olf[i * LDO + cc + u] = acc[u] * invL;
  __syncthreads();

  // Transposed coalesced store: 64 rows x 32 chans = 512 float4.
  for (int v = t; v < 512; v += 256) {
    int c = v >> 4, i4 = v & 15;
    float4 d;
    d.x = Olf[(i4 * 4 + 0) * LDO + c];
    d.y = Olf[(i4 * 4 + 1) * LDO + c];
    d.z = Olf[(i4 * 4 + 2) * LDO + c];
    d.w = Olf[(i4 * 4 + 3) * LDO + c];
    *(float4*)(out + (size_t)(b * CB + c0 + c) * NB + n0 + i4 * 4) = d;
  }
}

// ---------------------------------------------------------------------------
extern "C" void kernel_launch(void* const* d_in, const int* in_sizes, int n_in,
                              void* d_out, int out_size, void* d_ws, size_t ws_size,
                              hipStream_t stream) {
  const float* x  = (const float*)d_in[0];
  const float* Wq = (const float*)d_in[1];
  const float* bq = (const float*)d_in[2];
  const float* Wk = (const float*)d_in[3];
  const float* bk = (const float*)d_in[4];
  const float* Wv = (const float*)d_in[5];
  const float* bv = (const float*)d_in[6];
  float* out = (float*)d_out;

  const size_t qkv_elems = (size_t)BB * NB * CB;     // per tensor, bf16
  __bf16* Qt = (__bf16*)d_ws;
  __bf16* Kt = Qt + qkv_elems;
  __bf16* Vo = Kt + qkv_elems;
  char* ws_tail = (char*)(Vo + qkv_elems);
  size_t tail_sz = ws_size - 3 * qkv_elems * sizeof(__bf16);

  // nsplit partial buffers: nsplit*(B*N*C bf16 + B*N fp32). Deterministic.
  const size_t per_split = (size_t)BB * NB * CB * 2 + (size_t)BB * NB * 4;
  int nsplit = 8;
  while (nsplit > 1 && (size_t)nsplit * per_split > tail_sz) nsplit >>= 1;

  __bf16* Opart = (__bf16*)ws_tail;                        // [s][b][n][c] bf16
  float*  Ll = (float*)(Opart + (size_t)nsplit * BB * NB * CB);  // [s][b][n]
  const int ksz = NB / nsplit;

  const int qkv_smem  = (64 * LDP + 128 * LDP) * 2;                 // 52224 B
  const int attn_smem = 32768;                                      // 2x K tile
  const int comb_smem = 64 * LDO * 4;                               // 8448 B

  qkv_proj_kernel<<<dim3(NB / 64, BB, 3), 256, qkv_smem, stream>>>(
      x, Wq, bq, Wk, bk, Wv, bv, Qt, Kt, Vo);
  attn_part_kernel<<<dim3(NB / 128, BB, nsplit), 256, attn_smem, stream>>>(
      Qt, Kt, Vo, Opart, Ll, ksz);
  combine_kernel<<<dim3(NB / 64, BB, 4), 256, comb_smem, stream>>>(
      Opart, Ll, out, nsplit);
}

// Round 7
// 109.222 us; speedup vs baseline: 1.1794x; 1.1794x over previous
//
#include <hip/hip_runtime.h>

// ---------------------------------------------------------------------------
// SelfAttention (1x1x1 conv QKV + softmax attention), B=2, C=128, N=4096
// I/O: fp32. Internal: bf16 MFMA + fp32 accum. No max-shift softmax.
// Round-16:
//  * K2 = round-14 verified kernel (112.4us path), V-direct REVERTED
//    (R6 counters: V-direct made K2 latency-bound, 31->47.7us).
//  * K1 REWRITTEN fused: R6's counters imply K1+K3 ~ 81us of the total.
//    Old K1 read x 3x (48 MB) and stored via 32 scalar 2-B global
//    stores/thread. New K1: grid (128,2), 32-row n-tile, m-loop {Q,K,V}
//    inside -> x read once; epilogue via f32 LDS bounce -> coalesced
//    bf16x8 stores. Bias+scale in f32 at bounce-read (identical rounding).
// K1 qkv_fused: grid (128,2)   -> Qt[b][n][c] (x log2e), Kt, Vo bf16
// K2 attn_part: grid (32,2,8)  -> split-K partials (bf16) + l (fp32)
// K3 combine  : grid (64,2,4)  -> sum partials, /l, out[b][c][n] fp32
// ---------------------------------------------------------------------------

typedef __bf16 bf16x8 __attribute__((ext_vector_type(8)));
typedef __bf16 bf16x4v __attribute__((ext_vector_type(4)));
typedef float  f32x4  __attribute__((ext_vector_type(4)));

#define LDP 136   // row stride (bf16) for 128-wide LDS rows; 272B
#define LDO 33    // row stride (f32) for combine transpose (32-wide rows)
#define QB_STRIDE 132  // f32 bounce stride, Q/K layout [32 n][128 c]
#define VB_STRIDE 36   // f32 bounce stride, V layout  [128 c][32 n]

constexpr int CB = 128;
constexpr int NB = 4096;
constexpr int BB = 2;

__device__ __forceinline__ bf16x8 ldfrag(const __bf16* lds, int row, int koff, int ld) {
  return *(const bf16x8*)(lds + row * ld + koff);
}

__device__ __forceinline__ unsigned cvt_pk_bf16(float lo, float hi) {
  unsigned w;
  asm("v_cvt_pk_bf16_f32 %0, %1, %2" : "=v"(w) : "v"(lo), "v"(hi));
  return w;
}

// ---------------------------------------------------------------------------
// K1 (fused): one block = 32 n-rows x all 128 outputs x {Q,K,V}.
// x staged once (xT[32][LDP]); per m: stage W_m, MFMA, f32 bounce, coalesced
// bf16x8 store. Wave w: n-strip (w&1)*16, o-half (w>>1)*64.
// LDS: xT 8704 + Wl 34816 + bounce 18432 = 61952 B.
// Q output pre-scaled by log2(e) so K2 can use exp2 directly.
// ---------------------------------------------------------------------------
__global__ __launch_bounds__(256) void qkv_fused_kernel(
    const float* __restrict__ x,
    const float* __restrict__ Wq, const float* __restrict__ bq,
    const float* __restrict__ Wk, const float* __restrict__ bk,
    const float* __restrict__ Wv, const float* __restrict__ bv,
    __bf16* __restrict__ Qt, __bf16* __restrict__ Kt, __bf16* __restrict__ Vo)
{
  extern __shared__ __align__(16) char smem_raw[];
  __bf16* xT = (__bf16*)smem_raw;              // [32][LDP]
  __bf16* Wl = xT + 32 * LDP;                  // [128][LDP]
  float* bounce = (float*)(Wl + 128 * LDP);    // Q/K: [32][132] | V: [128][36]

  const int b  = blockIdx.y;
  const int n0 = blockIdx.x * 32;
  const int t  = threadIdx.x;
  const int lane = t & 63, w = t >> 6;
  const int l15 = lane & 15, quad = lane >> 4;
  const int nstrip = (w & 1) * 16;             // wave's n-strip
  const int obase  = (w >> 1) * 64;            // wave's o-half

  // Stage xT once: x[b][c][n0..n0+31] -> xT[i][c]. 1024 float4, 4/thread.
#pragma unroll
  for (int u = 0; u < 4; u++) {
    int v = t + u * 256;
    int c = v >> 3, i4 = v & 7;
    float4 d = *(const float4*)(x + (size_t)(b * CB + c) * NB + n0 + i4 * 4);
    xT[(i4 * 4 + 0) * LDP + c] = (__bf16)d.x;
    xT[(i4 * 4 + 1) * LDP + c] = (__bf16)d.y;
    xT[(i4 * 4 + 2) * LDP + c] = (__bf16)d.z;
    xT[(i4 * 4 + 3) * LDP + c] = (__bf16)d.w;
  }

  // Coalesced store of m's bounce (called AFTER the barrier following
  // m's bounce-write). Q/K: bf16x8 rows; V: 64-B segments.
  auto store_m = [&](int mm) {
    if (mm < 2) {
      const float* bp = (mm == 0) ? bq : bk;
      const float qs = (mm == 0) ? 1.4426950408889634f : 1.0f;
      __bf16* O = (mm == 0) ? Qt : Kt;
#pragma unroll
      for (int u = 0; u < 2; u++) {
        int v = t + u * 256;
        int n = v >> 4, c8 = (v & 15) * 8;
        f32x4 p0 = *(const f32x4*)(bounce + n * QB_STRIDE + c8);
        f32x4 p1 = *(const f32x4*)(bounce + n * QB_STRIDE + c8 + 4);
        float4 b0 = *(const float4*)(bp + c8);
        float4 b1 = *(const float4*)(bp + c8 + 4);
        bf16x8 o8;
        o8[0] = (__bf16)((p0[0] + b0.x) * qs);
        o8[1] = (__bf16)((p0[1] + b0.y) * qs);
        o8[2] = (__bf16)((p0[2] + b0.z) * qs);
        o8[3] = (__bf16)((p0[3] + b0.w) * qs);
        o8[4] = (__bf16)((p1[0] + b1.x) * qs);
        o8[5] = (__bf16)((p1[1] + b1.y) * qs);
        o8[6] = (__bf16)((p1[2] + b1.z) * qs);
        o8[7] = (__bf16)((p1[3] + b1.w) * qs);
        *(bf16x8*)(O + (size_t)(b * NB + n0 + n) * CB + c8) = o8;
      }
    } else {
#pragma unroll
      for (int u = 0; u < 2; u++) {
        int v = t + u * 256;
        int o = v >> 2, n8 = (v & 3) * 8;
        float bias = bv[o];
        f32x4 p0 = *(const f32x4*)(bounce + o * VB_STRIDE + n8);
        f32x4 p1 = *(const f32x4*)(bounce + o * VB_STRIDE + n8 + 4);
        bf16x8 o8;
        o8[0] = (__bf16)(p0[0] + bias);
        o8[1] = (__bf16)(p0[1] + bias);
        o8[2] = (__bf16)(p0[2] + bias);
        o8[3] = (__bf16)(p0[3] + bias);
        o8[4] = (__bf16)(p1[0] + bias);
        o8[5] = (__bf16)(p1[1] + bias);
        o8[6] = (__bf16)(p1[2] + bias);
        o8[7] = (__bf16)(p1[3] + bias);
        *(bf16x8*)(Vo + (size_t)(b * CB + o) * NB + n0 + n8) = o8;
      }
    }
  };

#pragma unroll
  for (int m = 0; m < 3; m++) {
    // Stage W_m (L2-resident after first blocks): 4096 float4, 16/thread.
    const float* W = (m == 0) ? Wq : (m == 1) ? Wk : Wv;
#pragma unroll
    for (int u = 0; u < 16; u++) {
      int v = t + u * 256;
      int o = v >> 5, c4 = v & 31;
      float4 d = *(const float4*)(W + o * 128 + c4 * 4);
      bf16x4v uu = {(__bf16)d.x, (__bf16)d.y, (__bf16)d.z, (__bf16)d.w};
      *(bf16x4v*)(Wl + o * LDP + c4 * 4) = uu;
    }
    if (m > 0) store_m(m - 1);   // overlaps W staging; reads prev bounce
    __syncthreads();             // Wl(m) ready; bounce(m-1) fully read

    if (m < 2) {
      // Q/K: a = xT row (n), b = Wl row (o). D: col o = l15, row n.
      f32x4 acc[4] = {(f32x4)0.0f, (f32x4)0.0f, (f32x4)0.0f, (f32x4)0.0f};
#pragma unroll
      for (int ks = 0; ks < 4; ks++) {
        int koff = ks * 32 + quad * 8;
        bf16x8 a = ldfrag(xT, nstrip + l15, koff, LDP);
#pragma unroll
        for (int ct = 0; ct < 4; ct++) {
          bf16x8 bb = ldfrag(Wl, obase + ct * 16 + l15, koff, LDP);
          acc[ct] = __builtin_amdgcn_mfma_f32_16x16x32_bf16(a, bb, acc[ct], 0, 0, 0);
        }
      }
#pragma unroll
      for (int ct = 0; ct < 4; ct++)
#pragma unroll
        for (int r = 0; r < 4; r++)
          bounce[(nstrip + quad * 4 + r) * QB_STRIDE + obase + ct * 16 + l15] =
              acc[ct][r];
    } else {
      // V: a = Wl row (o), b = xT row (n). D: col n = l15, row o.
      f32x4 acc[4] = {(f32x4)0.0f, (f32x4)0.0f, (f32x4)0.0f, (f32x4)0.0f};
#pragma unroll
      for (int ks = 0; ks < 4; ks++) {
        int koff = ks * 32 + quad * 8;
        bf16x8 bb = ldfrag(xT, nstrip + l15, koff, LDP);
#pragma unroll
        for (int rr = 0; rr < 4; rr++) {
          bf16x8 a = ldfrag(Wl, obase + rr * 16 + l15, koff, LDP);
          acc[rr] = __builtin_amdgcn_mfma_f32_16x16x32_bf16(a, bb, acc[rr], 0, 0, 0);
        }
      }
#pragma unroll
      for (int rr = 0; rr < 4; rr++)
#pragma unroll
        for (int r = 0; r < 4; r++)
          bounce[(obase + rr * 16 + quad * 4 + r) * VB_STRIDE + nstrip + l15] =
              acc[rr][r];
    }
    __syncthreads();             // bounce(m) ready for store / next stage
  }
  store_m(2);
}

// ---------------------------------------------------------------------------
// K2: split-K attention partials, no max-shift. grid (32, 2, nsplit), 256 thr
// (4 waves x 32 q-rows = 128 q-rows/block, each wave: two 16-row q-tiles).
// Swapped QK^T (S^T = mfma(K,Q)) -> lane (quad,l15) holds P[16kt+4*quad+r][l15].
// P -> PV A-fragment in registers via v_permlane{32,16}_swap (verified r14).
// K/V: double-buffered, unpadded + XOR-swizzle (byte ^= (row&7)<<4 on 16B
// units), reg-staged; loads issued at top of iter, LDS writes to the IDLE
// buffer after compute, ONE __syncthreads() per k-tile.
// LDS: 2 x (K 16384 + V 16384) = 65536 B.  [round-14 verified, 112.4us]
// ---------------------------------------------------------------------------
__global__ __launch_bounds__(256, 2) void attn_part_kernel(
    const __bf16* __restrict__ Qt,
    const __bf16* __restrict__ Kt,
    const __bf16* __restrict__ Vo,
    __bf16* __restrict__ Opart, float* __restrict__ Ll, int ksz)
{
  extern __shared__ __align__(16) char smem_raw[];
  // buffer bf: K at bf*32768, V at bf*32768 + 16384

  const int b  = blockIdx.y;
  const int q0 = blockIdx.x * 128;
  const int s  = blockIdx.z;
  const int k_base = s * ksz;
  const int nit = ksz >> 6;
  const int t  = threadIdx.x;
  const int lane = t & 63, w = t >> 6;             // w = 0..3
  const int l15 = lane & 15, quad = lane >> 4;
  const int row0 = w * 32;                         // wave's first local q-row
  const int xsw = (l15 & 7) << 4;                  // read-side swizzle term

  // Q fragments: two 16-row q-tiles per wave (MFMA B-operand layout).
  bf16x8 qf[2][4];
#pragma unroll
  for (int qt = 0; qt < 2; qt++)
#pragma unroll
    for (int cb = 0; cb < 4; cb++)
      qf[qt][cb] = *(const bf16x8*)(Qt +
          (size_t)(b * NB + q0 + row0 + qt * 16 + l15) * CB + cb * 32 + quad * 8);

  bf16x8 kr[4], vr[4];
  // Global loads of one 64-row K/V tile into regs (4+4 bf16x8 per thread).
  auto load_tile = [&](int m0) {
#pragma unroll
    for (int u = 0; u < 4; u++) {
      int v = t + u * 256;
      int j = v >> 4, c8 = v & 15;
      kr[u] = *(const bf16x8*)(Kt + (size_t)(b * NB + m0 + j) * CB + c8 * 8);
    }
#pragma unroll
    for (int u = 0; u < 4; u++) {
      int v = t + u * 256;
      int c = v >> 3, j8 = v & 7;
      vr[u] = *(const bf16x8*)(Vo + (size_t)(b * CB + c) * NB + m0 + j8 * 8);
    }
  };
  // Swizzled LDS write of the staged regs into buffer bf.
  auto write_tile = [&](int bf) {
    char* Kn = smem_raw + bf * 32768;
    char* Vn = Kn + 16384;
#pragma unroll
    for (int u = 0; u < 4; u++) {
      int v = t + u * 256;
      int j = v >> 4, c8 = v & 15;
      *(bf16x8*)(Kn + j * 256 + ((c8 * 16) ^ ((j & 7) << 4))) = kr[u];
    }
#pragma unroll
    for (int u = 0; u < 4; u++) {
      int v = t + u * 256;
      int c = v >> 3, j8 = v & 7;
      *(bf16x8*)(Vn + c * 128 + ((j8 * 16) ^ ((c & 7) << 4))) = vr[u];
    }
  };

  float lsum[2] = {0.0f, 0.0f};
  f32x4 o_acc[2][8];
#pragma unroll
  for (int qt = 0; qt < 2; qt++)
#pragma unroll
    for (int tt = 0; tt < 8; tt++) o_acc[qt][tt] = (f32x4)0.0f;

  // Stage tile 0 into buffer 0.
  load_tile(k_base);
  write_tile(0);
  __syncthreads();

  int cur = 0;
  for (int it = 0; it < nit; it++) {
    // Issue next tile's global loads now; LDS write happens after compute.
    if (it + 1 < nit) load_tile(k_base + (it + 1) * 64);

    const char* Kc = smem_raw + cur * 32768;
    const char* Vc = Kc + 16384;

    // S^T[64k x 32q] per wave: A = K-frag (row = k), B = Q-frag (col = q).
    f32x4 sacc[2][4];               // [qt][kt]
#pragma unroll
    for (int qt = 0; qt < 2; qt++)
#pragma unroll
      for (int kt = 0; kt < 4; kt++) sacc[qt][kt] = (f32x4)0.0f;
#pragma unroll
    for (int cb = 0; cb < 4; cb++) {
      const int xo = (cb * 64 + quad * 16) ^ xsw;
#pragma unroll
      for (int kt = 0; kt < 4; kt++) {
        bf16x8 af = *(const bf16x8*)(Kc + (kt * 16 + l15) * 256 + xo);
        sacc[0][kt] = __builtin_amdgcn_mfma_f32_16x16x32_bf16(af, qf[0][cb], sacc[0][kt], 0, 0, 0);
        sacc[1][kt] = __builtin_amdgcn_mfma_f32_16x16x32_bf16(af, qf[1][cb], sacc[1][kt], 0, 0, 0);
      }
    }

    // P = exp2(S^T) (Q carried log2e); build PV A-frags in-register.
    bf16x8 pa[2][2];                // [qt][ks]
#pragma unroll
    for (int qt = 0; qt < 2; qt++) {
      unsigned d[4][2];
#pragma unroll
      for (int kt = 0; kt < 4; kt++) {
        float p0 = exp2f(sacc[qt][kt][0]);
        float p1 = exp2f(sacc[qt][kt][1]);
        float p2 = exp2f(sacc[qt][kt][2]);
        float p3 = exp2f(sacc[qt][kt][3]);
        lsum[qt] += (p0 + p1) + (p2 + p3);
        d[kt][0] = cvt_pk_bf16(p0, p1);
        d[kt][1] = cvt_pk_bf16(p2, p3);
      }
#pragma unroll
      for (int ks = 0; ks < 2; ks++) {
        unsigned a0 = d[2 * ks][0], a1 = d[2 * ks][1];
        unsigned b0 = d[2 * ks + 1][0], b1 = d[2 * ks + 1][1];
        // vdst = a (d[2ks]), vsrc = b (d[2ks+1]):
        //   swap32: a=(a.q0,a.q1,b.q0,b.q1), b=(a.q2,a.q3,b.q2,b.q3)
        //   swap16: a=(a.q0,a.q2,b.q0,b.q2), b=(a.q1,a.q3,b.q1,b.q3)
        asm("v_permlane32_swap_b32 %0, %1" : "+v"(a0), "+v"(b0));
        asm("v_permlane16_swap_b32 %0, %1" : "+v"(a0), "+v"(b0));
        asm("v_permlane32_swap_b32 %0, %1" : "+v"(a1), "+v"(b1));
        asm("v_permlane16_swap_b32 %0, %1" : "+v"(a1), "+v"(b1));
        union { unsigned u[4]; bf16x8 v; } pk;
        pk.u[0] = a0; pk.u[1] = a1; pk.u[2] = b0; pk.u[3] = b1;
        pa[qt][ks] = pk.v;
      }
    }

    // O += P * V: each V fragment read feeds both q-tiles.
#pragma unroll
    for (int ks = 0; ks < 2; ks++) {
      const int xo = (ks * 64 + quad * 16) ^ xsw;
#pragma unroll
      for (int tt = 0; tt < 8; tt++) {
        bf16x8 bb = *(const bf16x8*)(Vc + (tt * 16 + l15) * 128 + xo);
        o_acc[0][tt] = __builtin_amdgcn_mfma_f32_16x16x32_bf16(pa[0][ks], bb, o_acc[0][tt], 0, 0, 0);
        o_acc[1][tt] = __builtin_amdgcn_mfma_f32_16x16x32_bf16(pa[1][ks], bb, o_acc[1][tt], 0, 0, 0);
      }
    }

    // Write next tile into the IDLE buffer; one barrier hands it over.
    if (it + 1 < nit) {
      write_tile(cur ^ 1);
      __syncthreads();
      cur ^= 1;
    }
  }

  // l-sum: lane holds the partial over its 16 k-slots; reduce across quads.
#pragma unroll
  for (int qt = 0; qt < 2; qt++) {
    lsum[qt] += __shfl_xor(lsum[qt], 16);
    lsum[qt] += __shfl_xor(lsum[qt], 32);
  }

  // Write unnormalized partial O (bf16, C/D layout direct) and l (fp32).
  const size_t obase = ((size_t)(s * BB + b) * NB + q0) * CB;
#pragma unroll
  for (int qt = 0; qt < 2; qt++)
#pragma unroll
    for (int tt = 0; tt < 8; tt++)
#pragma unroll
      for (int r = 0; r < 4; r++)
        Opart[obase + (size_t)(row0 + qt * 16 + quad * 4 + r) * CB + tt * 16 + l15] =
            (__bf16)o_acc[qt][tt][r];
  if (quad == 0) {
    const size_t lbase = (size_t)(s * BB + b) * NB + q0 + row0;
#pragma unroll
    for (int qt = 0; qt < 2; qt++)
      Ll[lbase + qt * 16 + l15] = lsum[qt];
  }
}

// ---------------------------------------------------------------------------
// K3: combine bf16 partials + normalize + transpose -> out[b][c][n] fp32.
// grid (64, 2, 4): 64 n-rows x 32 channels per block, 256 thr.
// LDS: Olf[64][LDO] f32 = 8448 B.
// ---------------------------------------------------------------------------
__global__ __launch_bounds__(256) void combine_kernel(
    const __bf16* __restrict__ Opart, const float* __restrict__ Ll,
    float* __restrict__ out, int nsplit)
{
  extern __shared__ __align__(16) char smem_raw[];
  float* Olf = (float*)smem_raw;  // Olf[i][c'], c' in [0,32)

  const int b  = blockIdx.y;
  const int n0 = blockIdx.x * 64;
  const int c0 = blockIdx.z * 32;
  const int t  = threadIdx.x;
  const int i  = t >> 2;          // row 0..63
  const int cc = (t & 3) * 8;     // 8 channels per thread

  float L = 0.0f;
  for (int s = 0; s < nsplit; s++)
    L += Ll[(size_t)(s * BB + b) * NB + n0 + i];

  float acc[8];
#pragma unroll
  for (int u = 0; u < 8; u++) acc[u] = 0.0f;
  for (int s = 0; s < nsplit; s++) {
    bf16x8 d = *(const bf16x8*)(Opart +
        ((size_t)(s * BB + b) * NB + n0 + i) * CB + c0 + cc);
#pragma unroll
    for (int u = 0; u < 8; u++) acc[u] += (float)d[u];
  }
  float invL = 1.0f / L;
#pragma unroll
  for (int u = 0; u < 8; u++) Olf[i * LDO + cc + u] = acc[u] * invL;
  __syncthreads();

  // Transposed coalesced store: 64 rows x 32 chans = 512 float4.
  for (int v = t; v < 512; v += 256) {
    int c = v >> 4, i4 = v & 15;
    float4 d;
    d.x = Olf[(i4 * 4 + 0) * LDO + c];
    d.y = Olf[(i4 * 4 + 1) * LDO + c];
    d.z = Olf[(i4 * 4 + 2) * LDO + c];
    d.w = Olf[(i4 * 4 + 3) * LDO + c];
    *(float4*)(out + (size_t)(b * CB + c0 + c) * NB + n0 + i4 * 4) = d;
  }
}

// ---------------------------------------------------------------------------
extern "C" void kernel_launch(void* const* d_in, const int* in_sizes, int n_in,
                              void* d_out, int out_size, void* d_ws, size_t ws_size,
                              hipStream_t stream) {
  const float* x  = (const float*)d_in[0];
  const float* Wq = (const float*)d_in[1];
  const float* bq = (const float*)d_in[2];
  const float* Wk = (const float*)d_in[3];
  const float* bk = (const float*)d_in[4];
  const float* Wv = (const float*)d_in[5];
  const float* bv = (const float*)d_in[6];
  float* out = (float*)d_out;

  const size_t qkv_elems = (size_t)BB * NB * CB;     // per tensor, bf16
  __bf16* Qt = (__bf16*)d_ws;
  __bf16* Kt = Qt + qkv_elems;
  __bf16* Vo = Kt + qkv_elems;
  char* ws_tail = (char*)(Vo + qkv_elems);
  size_t tail_sz = ws_size - 3 * qkv_elems * sizeof(__bf16);

  // nsplit partial buffers: nsplit*(B*N*C bf16 + B*N fp32). Deterministic.
  const size_t per_split = (size_t)BB * NB * CB * 2 + (size_t)BB * NB * 4;
  int nsplit = 8;
  while (nsplit > 1 && (size_t)nsplit * per_split > tail_sz) nsplit >>= 1;

  __bf16* Opart = (__bf16*)ws_tail;                        // [s][b][n][c] bf16
  float*  Ll = (float*)(Opart + (size_t)nsplit * BB * NB * CB);  // [s][b][n]
  const int ksz = NB / nsplit;

  const int qkv_smem  = 32 * LDP * 2 + 128 * LDP * 2 + 128 * VB_STRIDE * 4; // 61952
  const int attn_smem = 65536;                                      // 2x(K+V)
  const int comb_smem = 64 * LDO * 4;                               // 8448 B

  qkv_fused_kernel<<<dim3(NB / 32, BB), 256, qkv_smem, stream>>>(
      x, Wq, bq, Wk, bk, Wv, bv, Qt, Kt, Vo);
  attn_part_kernel<<<dim3(NB / 128, BB, nsplit), 256, attn_smem, stream>>>(
      Qt, Kt, Vo, Opart, Ll, ksz);
  combine_kernel<<<dim3(NB / 64, BB, 4), 256, comb_smem, stream>>>(
      Opart, Ll, out, nsplit);
}